// Round 2
// baseline (208.325 us; speedup 1.0000x reference)
//
#include <hip/hip_runtime.h>

#define NN 20
#define DD 64
#define CAP 32
#define NP 125          // WIDTH^3
#define NV (NN*NN*NN)   // 8000

// ---------------------------------------------------------------------------
// Kernel A: per-voxel projections.
//   Q[v]    = SE[v] @ Wq + bq
//   Kmap[v] = SE[v] @ Wk[96:160]   (bias lives in k_rel)
//   Vmap[v] = SE[v] @ Wv[96:160]
// ---------------------------------------------------------------------------
__global__ __launch_bounds__(256) void qkv_maps(
        const float* __restrict__ SE,
        const float* __restrict__ Wq, const float* __restrict__ bq,
        const float* __restrict__ Wk, const float* __restrict__ Wv,
        float* __restrict__ Q, float* __restrict__ Km, float* __restrict__ Vm) {
    __shared__ float se_s[4][DD];
    const int w = threadIdx.x >> 6;
    const int c = threadIdx.x & 63;
    const int v = blockIdx.x * 4 + w;
    se_s[w][c] = SE[v * DD + c];
    __syncthreads();
    float aq = bq[c], ak = 0.f, av = 0.f;
#pragma unroll 8
    for (int d = 0; d < DD; ++d) {
        const float s = se_s[w][d];
        aq = fmaf(s, Wq[d * 64 + c], aq);
        ak = fmaf(s, Wk[(96 + d) * 64 + c], ak);
        av = fmaf(s, Wv[(96 + d) * 64 + c], av);
    }
    Q[v * 64 + c]  = aq;
    Km[v * 64 + c] = ak;
    Vm[v * 64 + c] = av;
}

// ---------------------------------------------------------------------------
// Kernel B: relative-position K/V tables (125 x 64 each).
//   relpos_flat[p=(d3,d4,d5)] = concat(rw[d3], rw[d4], rw[d5])  (96 dims)
// ---------------------------------------------------------------------------
__global__ __launch_bounds__(64) void rel_kv(
        const float* __restrict__ relpos_w,
        const float* __restrict__ Wk, const float* __restrict__ bk,
        const float* __restrict__ Wv, const float* __restrict__ bv,
        float* __restrict__ k_rel, float* __restrict__ v_rel) {
    const int p = blockIdx.x;
    const int c = threadIdx.x;
    const int d3 = p / 25;
    const int d4 = (p / 5) % 5;
    const int d5 = p % 5;
    float ak = bk[c], av = bv[c];
#pragma unroll
    for (int t = 0; t < 96; ++t) {
        const int blk = t >> 5, off = t & 31;
        const int row = (blk == 0) ? d3 : (blk == 1) ? d4 : d5;
        const float r = relpos_w[row * CAP + off];
        ak = fmaf(r, Wk[t * 64 + c], ak);
        av = fmaf(r, Wv[t * 64 + c], av);
    }
    k_rel[p * 64 + c] = ak;
    v_rel[p * 64 + c] = av;
}

// ---------------------------------------------------------------------------
// Kernel C: attention. One 64-lane wave per voxel, 4 waves per block.
// REFERENCE QUIRK (must replicate): for p = d3*25 + d4*5 + d5,
//   - embedding gather uses SWAPPED x/y digits: nb = (x+d4-2, y+d3-2, z+d5-2),
//     zero (padding) if outside [0,19]^3
//   - mask uses UNSWAPPED digits: valid iff (x+d3-2, y+d4-2, z+d5-2) in [1,19]^3
//   - relpos table uses unswapped digits (handled in rel_kv)
// Masked logit = -1e9 -> expf underflows to exactly 0, so masked p's can be
// skipped in the V-accumulation.
// ---------------------------------------------------------------------------
__global__ __launch_bounds__(256) void attn(
        const float* __restrict__ Q, const float* __restrict__ Km,
        const float* __restrict__ Vm,
        const float* __restrict__ k_rel, const float* __restrict__ v_rel,
        const float* __restrict__ Wo, const float* __restrict__ bo,
        float* __restrict__ out) {
    const int lane = threadIdx.x & 63;
    const int wv   = threadIdx.x >> 6;
    const int v    = blockIdx.x * 4 + wv;
    const int z = v % NN;
    const int y = (v / NN) % NN;
    const int x = v / (NN * NN);

    const float q = Q[v * 64 + lane];

    // ---- geometry for p0 = lane, p1 = lane + 64 ----
    const int p0 = lane;
    const int p1 = lane + 64;
    const int p1c = (p1 < NP) ? p1 : (NP - 1);

    int d3 = p0 / 25, d4 = (p0 / 5) % 5, d5 = p0 % 5;
    int MX = x + d3 - 2, MY = y + d4 - 2, MZ = z + d5 - 2;
    const bool mv0 = (MX >= 1 && MX <= 19 && MY >= 1 && MY <= 19 &&
                      MZ >= 1 && MZ <= 19);
    int NX = x + d4 - 2, NY = y + d3 - 2, NZ = z + d5 - 2;
    const bool ia0 = (NX >= 0 && NX <= 19 && NY >= 0 && NY <= 19 &&
                      NZ >= 0 && NZ <= 19);
    const int nb0 = ia0 ? ((NX * NN + NY) * NN + NZ) : 0;

    d3 = p1c / 25; d4 = (p1c / 5) % 5; d5 = p1c % 5;
    MX = x + d3 - 2; MY = y + d4 - 2; MZ = z + d5 - 2;
    const bool mv1 = (p1 < NP) && (MX >= 1 && MX <= 19 && MY >= 1 &&
                      MY <= 19 && MZ >= 1 && MZ <= 19);
    NX = x + d4 - 2; NY = y + d3 - 2; NZ = z + d5 - 2;
    const bool ia1 = (NX >= 0 && NX <= 19 && NY >= 0 && NY <= 19 &&
                      NZ >= 0 && NZ <= 19);
    const int nb1 = ia1 ? ((NX * NN + NY) * NN + NZ) : 0;

    const float g0 = ia0 ? 1.f : 0.f;
    const float g1 = ia1 ? 1.f : 0.f;

    const float4* __restrict__ K0 = (const float4*)(Km + nb0 * 64);
    const float4* __restrict__ K1 = (const float4*)(Km + nb1 * 64);
    const float4* __restrict__ R0 = (const float4*)(k_rel + p0 * 64);
    const float4* __restrict__ R1 = (const float4*)(k_rel + p1c * 64);

    float acc0 = 0.f, acc1 = 0.f;
#pragma unroll
    for (int i = 0; i < 16; ++i) {
        const float qx = __shfl(q, 4 * i + 0);
        const float qy = __shfl(q, 4 * i + 1);
        const float qz = __shfl(q, 4 * i + 2);
        const float qw = __shfl(q, 4 * i + 3);
        const float4 k0 = K0[i], r0 = R0[i];
        acc0 = fmaf(fmaf(k0.x, g0, r0.x), qx, acc0);
        acc0 = fmaf(fmaf(k0.y, g0, r0.y), qy, acc0);
        acc0 = fmaf(fmaf(k0.z, g0, r0.z), qz, acc0);
        acc0 = fmaf(fmaf(k0.w, g0, r0.w), qw, acc0);
        const float4 k1 = K1[i], r1 = R1[i];
        acc1 = fmaf(fmaf(k1.x, g1, r1.x), qx, acc1);
        acc1 = fmaf(fmaf(k1.y, g1, r1.y), qy, acc1);
        acc1 = fmaf(fmaf(k1.z, g1, r1.z), qz, acc1);
        acc1 = fmaf(fmaf(k1.w, g1, r1.w), qw, acc1);
    }
    float l0 = mv0 ? acc0 : -1e9f;
    float l1 = mv1 ? acc1 : -1e9f;

    // ---- softmax over 125 ----
    float m = fmaxf(l0, l1);
#pragma unroll
    for (int d = 1; d < 64; d <<= 1) m = fmaxf(m, __shfl_xor(m, d));
    const float e0 = __expf(l0 - m);
    const float e1 = __expf(l1 - m);
    float ssum = e0 + e1;
#pragma unroll
    for (int d = 1; d < 64; d <<= 1) ssum += __shfl_xor(ssum, d);
    const float inv = 1.f / ssum;
    const float s0 = e0 * inv;
    const float s1 = e1 * inv;

    // ---- weighted V sum: lane = channel ----
    float rw = 0.f;
    for (int p = 0; p < NP; ++p) {
        const int e3 = p / 25, e4 = (p / 5) % 5, e5 = p % 5;
        const int mX = x + e3 - 2, mY = y + e4 - 2, mZ = z + e5 - 2;
        const bool mv = (mX >= 1 && mX <= 19 && mY >= 1 && mY <= 19 &&
                         mZ >= 1 && mZ <= 19);
        if (!mv) continue;  // wave-uniform: masked score is exactly 0
        const float sc = (p < 64) ? __shfl(s0, p) : __shfl(s1, p - 64);
        const int gX = x + e4 - 2, gY = y + e3 - 2, gZ = z + e5 - 2;
        const bool ia = (gX >= 0 && gX <= 19 && gY >= 0 && gY <= 19 &&
                         gZ >= 0 && gZ <= 19);
        const float vm = ia ? Vm[((gX * NN + gY) * NN + gZ) * 64 + lane] : 0.f;
        rw = fmaf(sc, v_rel[p * 64 + lane] + vm, rw);
    }

    // ---- output projection: out = rw @ Wo + bo ----
    float o = bo[lane];
#pragma unroll
    for (int c = 0; c < 64; ++c) {
        const float r = __shfl(rw, c);
        o = fmaf(r, Wo[c * 64 + lane], o);
    }
    out[v * 64 + lane] = o;
}

// ---------------------------------------------------------------------------
extern "C" void kernel_launch(void* const* d_in, const int* in_sizes, int n_in,
                              void* d_out, int out_size, void* d_ws, size_t ws_size,
                              hipStream_t stream) {
    const float* SE  = (const float*)d_in[0];
    const float* rpw = (const float*)d_in[1];
    const float* Wq  = (const float*)d_in[2];
    const float* bq  = (const float*)d_in[3];
    const float* Wk  = (const float*)d_in[4];
    const float* bk  = (const float*)d_in[5];
    const float* Wv  = (const float*)d_in[6];
    const float* bv  = (const float*)d_in[7];
    const float* Wo  = (const float*)d_in[8];
    const float* bo  = (const float*)d_in[9];
    float* out = (float*)d_out;

    float* ws    = (float*)d_ws;
    float* Q     = ws;                 // 8000*64
    float* Kmap  = ws + 512000;        // 8000*64
    float* Vmap  = ws + 1024000;       // 8000*64
    float* k_rel = ws + 1536000;       // 125*64
    float* v_rel = ws + 1544000;       // 125*64

    qkv_maps<<<NV / 4, 256, 0, stream>>>(SE, Wq, bq, Wk, Wv, Q, Kmap, Vmap);
    rel_kv<<<NP, 64, 0, stream>>>(rpw, Wk, bk, Wv, bv, k_rel, v_rel);
    attn<<<NV / 4, 256, 0, stream>>>(Q, Kmap, Vmap, k_rel, v_rel, Wo, bo, out);
}

// Round 3
// 194.566 us; speedup vs baseline: 1.0707x; 1.0707x over previous
//
#include <hip/hip_runtime.h>

#define NN 20
#define NP 125          // 5^3 window
#define NV (NN*NN*NN)   // 8000

// ---------------------------------------------------------------------------
// prep: blocks 0..124  -> k_rel[p][c]  = bk + relpos_flat[p] @ Wk[0:96]
//                         vrelW[p][c]  = (bv + relpos_flat[p] @ Wv[0:96]) @ Wo
//       blocks 125..188 -> Wvo[d][c]   = Wv[96+d][:] @ Wo     (64x64)
// ---------------------------------------------------------------------------
__global__ __launch_bounds__(64) void prep(
        const float* __restrict__ rpw,
        const float* __restrict__ Wk, const float* __restrict__ bk,
        const float* __restrict__ Wv, const float* __restrict__ bv,
        const float* __restrict__ Wo,
        float* __restrict__ k_rel, float* __restrict__ vrelW,
        float* __restrict__ Wvo) {
    const int c = threadIdx.x;
    if (blockIdx.x < NP) {
        const int p = blockIdx.x;
        const int d3 = p / 25, d4 = (p / 5) % 5, d5 = p % 5;
        __shared__ float vtmp[64];
        float ak = bk[c], av = bv[c];
#pragma unroll
        for (int t = 0; t < 96; ++t) {
            const int blk = t >> 5, off = t & 31;
            const int row = (blk == 0) ? d3 : (blk == 1) ? d4 : d5;
            const float r = rpw[row * 32 + off];
            ak = fmaf(r, Wk[t * 64 + c], ak);
            av = fmaf(r, Wv[t * 64 + c], av);
        }
        k_rel[p * 64 + c] = ak;
        vtmp[c] = av;
        __syncthreads();
        float o = 0.f;
#pragma unroll 8
        for (int e = 0; e < 64; ++e)
            o = fmaf(vtmp[e], Wo[e * 64 + c], o);
        vrelW[p * 64 + c] = o;
    } else {
        const int d = blockIdx.x - NP;
        float acc = 0.f;
#pragma unroll 8
        for (int e = 0; e < 64; ++e)
            acc = fmaf(Wv[(96 + d) * 64 + e], Wo[e * 64 + c], acc);
        Wvo[d * 64 + c] = acc;
    }
}

// ---------------------------------------------------------------------------
// qkv2: Q = SE@Wq + bq ; Km = SE@Wk[96:] ; VW = SE@Wvo
// 250 blocks x 256 threads, 32 voxels/block (8 per wave).
// SE staged coalesced into padded LDS; weights loaded once per d-step and
// FMA'd into 8 voxel accumulators (8x weight-traffic amortization).
// ---------------------------------------------------------------------------
__global__ __launch_bounds__(256) void qkv2(
        const float* __restrict__ SE,
        const float* __restrict__ Wq, const float* __restrict__ bq,
        const float* __restrict__ Wk, const float* __restrict__ Wvo,
        float* __restrict__ Q, float* __restrict__ Km, float* __restrict__ VW) {
    __shared__ float se_s[32][65];
    const int t = threadIdx.x;
    const int vbase = blockIdx.x * 32;
    {   // stage 32x64 floats = 512 float4, 2 per thread
        const float4* __restrict__ src = (const float4*)(SE + vbase * 64);
        const float4 a = src[t];
        const float4 b = src[t + 256];
        const int r0 = t >> 4,        c0 = (t & 15) * 4;
        const int r1 = (t + 256) >> 4, c1 = c0;
        se_s[r0][c0 + 0] = a.x; se_s[r0][c0 + 1] = a.y;
        se_s[r0][c0 + 2] = a.z; se_s[r0][c0 + 3] = a.w;
        se_s[r1][c1 + 0] = b.x; se_s[r1][c1 + 1] = b.y;
        se_s[r1][c1 + 2] = b.z; se_s[r1][c1 + 3] = b.w;
    }
    __syncthreads();
    const int lane = t & 63, w = t >> 6;
    float aq[8], ak[8], av[8];
#pragma unroll
    for (int j = 0; j < 8; ++j) { aq[j] = bq[lane]; ak[j] = 0.f; av[j] = 0.f; }
#pragma unroll 8
    for (int d = 0; d < 64; ++d) {
        const float wq = Wq[d * 64 + lane];
        const float wk = Wk[(96 + d) * 64 + lane];
        const float wv = Wvo[d * 64 + lane];
#pragma unroll
        for (int j = 0; j < 8; ++j) {
            const float s = se_s[w * 8 + j][d];   // uniform addr -> broadcast
            aq[j] = fmaf(s, wq, aq[j]);
            ak[j] = fmaf(s, wk, ak[j]);
            av[j] = fmaf(s, wv, av[j]);
        }
    }
#pragma unroll
    for (int j = 0; j < 8; ++j) {
        const int v = vbase + w * 8 + j;
        Q[v * 64 + lane]  = aq[j];
        Km[v * 64 + lane] = ak[j];
        VW[v * 64 + lane] = av[j];
    }
}

// ---------------------------------------------------------------------------
// attn2: one wave per voxel. QK logits (lane = 2 neighbors) -> butterfly
// softmax over 125 -> straight-line unrolled weighted-V gather (lane = chan).
// Output projection is pre-folded into VW/vrelW; just + bo here.
// REFERENCE QUIRKS replicated: gather uses swapped x/y digits (d4,d3,d5),
// mask uses (d3,d4,d5) in [1,19]; out-of-array gather contributes 0 (padding).
// ---------------------------------------------------------------------------
__global__ __launch_bounds__(256) void attn2(
        const float* __restrict__ Q, const float* __restrict__ Km,
        const float* __restrict__ VW,
        const float* __restrict__ k_rel, const float* __restrict__ vrelW,
        const float* __restrict__ bo,
        float* __restrict__ out) {
    const int lane = threadIdx.x & 63;
    const int wv   = threadIdx.x >> 6;
    const int v    = blockIdx.x * 4 + wv;
    const int z = v % NN;
    const int y = (v / NN) % NN;
    const int x = v / (NN * NN);

    const float q = Q[v * 64 + lane];

    // ---- geometry for p0 = lane, p1 = lane + 64 ----
    const int p0 = lane;
    const int p1 = lane + 64;
    const int p1c = (p1 < NP) ? p1 : (NP - 1);

    int d3 = p0 / 25, d4 = (p0 / 5) % 5, d5 = p0 % 5;
    int MX = x + d3 - 2, MY = y + d4 - 2, MZ = z + d5 - 2;
    const bool mv0 = (MX >= 1 && MX <= 19 && MY >= 1 && MY <= 19 &&
                      MZ >= 1 && MZ <= 19);
    int NX = x + d4 - 2, NY = y + d3 - 2, NZ = z + d5 - 2;
    const bool ia0 = (NX >= 0 && NX <= 19 && NY >= 0 && NY <= 19 &&
                      NZ >= 0 && NZ <= 19);
    const int nb0 = ia0 ? ((NX * NN + NY) * NN + NZ) : 0;

    d3 = p1c / 25; d4 = (p1c / 5) % 5; d5 = p1c % 5;
    MX = x + d3 - 2; MY = y + d4 - 2; MZ = z + d5 - 2;
    const bool mv1 = (p1 < NP) && (MX >= 1 && MX <= 19 && MY >= 1 &&
                      MY <= 19 && MZ >= 1 && MZ <= 19);
    NX = x + d4 - 2; NY = y + d3 - 2; NZ = z + d5 - 2;
    const bool ia1 = (NX >= 0 && NX <= 19 && NY >= 0 && NY <= 19 &&
                      NZ >= 0 && NZ <= 19);
    const int nb1 = ia1 ? ((NX * NN + NY) * NN + NZ) : 0;

    const float g0 = ia0 ? 1.f : 0.f;
    const float g1 = ia1 ? 1.f : 0.f;

    const float4* __restrict__ K0 = (const float4*)(Km + nb0 * 64);
    const float4* __restrict__ K1 = (const float4*)(Km + nb1 * 64);
    const float4* __restrict__ R0 = (const float4*)(k_rel + p0 * 64);
    const float4* __restrict__ R1 = (const float4*)(k_rel + p1c * 64);

    float acc0 = 0.f, acc1 = 0.f;
#pragma unroll
    for (int i = 0; i < 16; ++i) {
        const float qx = __shfl(q, 4 * i + 0);
        const float qy = __shfl(q, 4 * i + 1);
        const float qz = __shfl(q, 4 * i + 2);
        const float qw = __shfl(q, 4 * i + 3);
        const float4 k0 = K0[i], r0 = R0[i];
        acc0 = fmaf(fmaf(k0.x, g0, r0.x), qx, acc0);
        acc0 = fmaf(fmaf(k0.y, g0, r0.y), qy, acc0);
        acc0 = fmaf(fmaf(k0.z, g0, r0.z), qz, acc0);
        acc0 = fmaf(fmaf(k0.w, g0, r0.w), qw, acc0);
        const float4 k1 = K1[i], r1 = R1[i];
        acc1 = fmaf(fmaf(k1.x, g1, r1.x), qx, acc1);
        acc1 = fmaf(fmaf(k1.y, g1, r1.y), qy, acc1);
        acc1 = fmaf(fmaf(k1.z, g1, r1.z), qz, acc1);
        acc1 = fmaf(fmaf(k1.w, g1, r1.w), qw, acc1);
    }
    const float l0 = mv0 ? acc0 : -1e9f;
    const float l1 = mv1 ? acc1 : -1e9f;

    // ---- softmax over 125 ----
    float m = fmaxf(l0, l1);
#pragma unroll
    for (int d = 1; d < 64; d <<= 1) m = fmaxf(m, __shfl_xor(m, d));
    const float e0 = __expf(l0 - m);
    const float e1 = __expf(l1 - m);
    float ssum = e0 + e1;
#pragma unroll
    for (int d = 1; d < 64; d <<= 1) ssum += __shfl_xor(ssum, d);
    const float inv = 1.f / ssum;
    const float s0 = e0 * inv;
    const float s1 = e1 * inv;

    // ---- weighted V sum: lane = channel, straight-line, 5 accumulators ----
    bool xin[5], yin[5], zin[5];
#pragma unroll
    for (int o = 0; o < 5; ++o) {
        xin[o] = ((unsigned)(x + o - 2) <= 19u);
        yin[o] = ((unsigned)(y + o - 2) <= 19u);
        zin[o] = ((unsigned)(z + o - 2) <= 19u);
    }
    float rwA[5] = {0.f, 0.f, 0.f, 0.f, 0.f};
#pragma unroll
    for (int p = 0; p < NP; ++p) {
        const int e3 = p / 25, e4 = (p / 5) % 5, e5 = p % 5;
        const float sc = (p < 64) ? __shfl(s0, p) : __shfl(s1, p - 64);
        const bool ia = xin[e4] && yin[e3] && zin[e5];
        const int nb = ia ? (v + (e4 - 2) * 400 + (e3 - 2) * 20 + (e5 - 2)) : v;
        const float scg = ia ? sc : 0.f;
        float a = rwA[p % 5];
        a = fmaf(sc, vrelW[p * 64 + lane], a);
        a = fmaf(scg, VW[nb * 64 + lane], a);
        rwA[p % 5] = a;
    }
    const float rw = ((rwA[0] + rwA[1]) + (rwA[2] + rwA[3])) + rwA[4];
    out[v * 64 + lane] = rw + bo[lane];
}

// ---------------------------------------------------------------------------
extern "C" void kernel_launch(void* const* d_in, const int* in_sizes, int n_in,
                              void* d_out, int out_size, void* d_ws, size_t ws_size,
                              hipStream_t stream) {
    const float* SE  = (const float*)d_in[0];
    const float* rpw = (const float*)d_in[1];
    const float* Wq  = (const float*)d_in[2];
    const float* bq  = (const float*)d_in[3];
    const float* Wk  = (const float*)d_in[4];
    const float* bk  = (const float*)d_in[5];
    const float* Wv  = (const float*)d_in[6];
    const float* bv  = (const float*)d_in[7];
    const float* Wo  = (const float*)d_in[8];
    const float* bo  = (const float*)d_in[9];
    float* out = (float*)d_out;

    float* ws    = (float*)d_ws;
    float* Q     = ws;                 // 8000*64
    float* Km    = ws + 512000;        // 8000*64
    float* VW    = ws + 1024000;       // 8000*64
    float* k_rel = ws + 1536000;       // 125*64
    float* vrelW = ws + 1544000;       // 125*64
    float* Wvo   = ws + 1552000;       // 64*64

    prep<<<NP + 64, 64, 0, stream>>>(rpw, Wk, bk, Wv, bv, Wo, k_rel, vrelW, Wvo);
    qkv2<<<NV / 32, 256, 0, stream>>>(SE, Wq, bq, Wk, Wvo, Q, Km, VW);
    attn2<<<NV / 4, 256, 0, stream>>>(Q, Km, VW, k_rel, vrelW, bo, out);
}